// Round 1
// baseline (679.720 us; speedup 1.0000x reference)
//
#include <hip/hip_runtime.h>
#include <hip/hip_bf16.h>
#include <math.h>
#include <stdint.h>

#define DIM 2048
#define HID 8192
#define NTOK 8192
#define KCAP 4096

typedef __attribute__((ext_vector_type(4))) float floatx4;
typedef __attribute__((ext_vector_type(8))) short short8;

__device__ __forceinline__ unsigned short bf16b(float f) {
    union { float f; unsigned int u; } v; v.f = f;
    unsigned int r = v.u + 0x7fffu + ((v.u >> 16) & 1u);   // RNE
    return (unsigned short)(r >> 16);
}

typedef const __attribute__((address_space(1))) unsigned int* gu32p;
typedef __attribute__((address_space(3))) unsigned int* lu32p;
__device__ __forceinline__ void load16_lds(const void* g, void* l) {
    __builtin_amdgcn_global_load_lds((gu32p)g, (lu32p)l, 16, 0, 0);
}

// ---------------- RMSNorm + router logit ----------------
__launch_bounds__(256)
__global__ void rmsnorm_router(const float* __restrict__ x,
                               const float* __restrict__ nw,
                               const float* __restrict__ rw,
                               const float* __restrict__ rb,
                               unsigned short* __restrict__ xn,
                               float* __restrict__ logits) {
    const int row = blockIdx.x;
    const int t = threadIdx.x;
    const float4* x4 = (const float4*)(x + (size_t)row * DIM);
    float4 a = x4[t];
    float4 b = x4[t + 256];
    float ss = a.x*a.x + a.y*a.y + a.z*a.z + a.w*a.w
             + b.x*b.x + b.y*b.y + b.z*b.z + b.w*b.w;
    for (int off = 32; off > 0; off >>= 1) ss += __shfl_down(ss, off, 64);
    __shared__ float red[4];
    int wave = t >> 6, lane = t & 63;
    if (lane == 0) red[wave] = ss;
    __syncthreads();
    float tot = red[0] + red[1] + red[2] + red[3];
    float rs = rsqrtf(tot / (float)DIM + 1e-6f);

    const float4* nw4 = (const float4*)nw;
    const float4* rw4 = (const float4*)rw;
    float4 w0 = nw4[t], w1 = nw4[t + 256];
    float4 r0 = rw4[t], r1 = rw4[t + 256];
    float4 n0, n1;
    n0.x = a.x*rs*w0.x; n0.y = a.y*rs*w0.y; n0.z = a.z*rs*w0.z; n0.w = a.w*rs*w0.w;
    n1.x = b.x*rs*w1.x; n1.y = b.y*rs*w1.y; n1.z = b.z*rs*w1.z; n1.w = b.w*rs*w1.w;
    float dot = n0.x*r0.x + n0.y*r0.y + n0.z*r0.z + n0.w*r0.w
              + n1.x*r1.x + n1.y*r1.y + n1.z*r1.z + n1.w*r1.w;

    unsigned short* xr = xn + (size_t)row * DIM;
    uint2 p0, p1;
    p0.x = (unsigned)bf16b(n0.x) | ((unsigned)bf16b(n0.y) << 16);
    p0.y = (unsigned)bf16b(n0.z) | ((unsigned)bf16b(n0.w) << 16);
    p1.x = (unsigned)bf16b(n1.x) | ((unsigned)bf16b(n1.y) << 16);
    p1.y = (unsigned)bf16b(n1.z) | ((unsigned)bf16b(n1.w) << 16);
    *(uint2*)(xr + 4*t)        = p0;
    *(uint2*)(xr + 4*t + 1024) = p1;

    for (int off = 32; off > 0; off >>= 1) dot += __shfl_down(dot, off, 64);
    __syncthreads();                 // protect red reuse
    if (lane == 0) red[wave] = dot;
    __syncthreads();
    if (t == 0) logits[row] = red[0] + red[1] + red[2] + red[3] + rb[0];
}

// ---------------- fp32 -> bf16 transpose (dst[c][r] = src[r][c]) ----------------
__launch_bounds__(256)
__global__ void transpose_bf16(const float* __restrict__ src, unsigned short* __restrict__ dst,
                               int R, int C) {
    __shared__ float tile[32][33];
    int c0 = blockIdx.x * 32, r0 = blockIdx.y * 32;
    int tx = threadIdx.x, ty = threadIdx.y;
    #pragma unroll
    for (int i = 0; i < 32; i += 8)
        tile[ty + i][tx] = src[(size_t)(r0 + ty + i) * C + c0 + tx];
    __syncthreads();
    #pragma unroll
    for (int i = 0; i < 32; i += 8)
        dst[(size_t)(c0 + ty + i) * R + r0 + tx] = bf16b(tile[tx][ty + i]);
}

// ---------------- exact rank counting (jax top_k tie-break: lower index wins) ----------------
#define JCHUNK 1024
__launch_bounds__(256)
__global__ void rank_partial(const float* __restrict__ logits, int* __restrict__ cnt) {
    __shared__ float ls[JCHUNK];
    const int j0 = blockIdx.y * JCHUNK;
    for (int j = threadIdx.x; j < JCHUNK; j += 256) ls[j] = logits[j0 + j];
    __syncthreads();
    const int i = blockIdx.x * 256 + threadIdx.x;
    const float my = logits[i];
    int c = 0;
    #pragma unroll 8
    for (int j = 0; j < JCHUNK; j++) {
        float v = ls[j];
        c += (v > my) || (v == my && (j0 + j) < i);
    }
    atomicAdd(&cnt[i], c);
}

__launch_bounds__(256)
__global__ void select_compact(const int* __restrict__ cnt, int* __restrict__ counter,
                               int* __restrict__ sel_idx, int* __restrict__ slot_map) {
    const int i = blockIdx.x * 256 + threadIdx.x;
    const bool sel = cnt[i] < KCAP;
    unsigned long long m = __ballot(sel);
    int lane = threadIdx.x & 63;
    int base = 0;
    if (lane == 0) base = atomicAdd(counter, (int)__popcll(m));
    base = __shfl(base, 0, 64);
    if (sel) {
        int pos = base + (int)__popcll(m & ((1ull << lane) - 1ull));
        sel_idx[pos] = i;
        slot_map[i] = pos;
    }
}

// ---------------- gather selected rows ----------------
__launch_bounds__(256)
__global__ void gather_rows(const unsigned short* __restrict__ xn, const int* __restrict__ sel_idx,
                            unsigned short* __restrict__ xg) {
    const int slot = blockIdx.x;
    const int src = sel_idx[slot];
    const uint4* s = (const uint4*)(xn + (size_t)src * DIM);
    uint4* d = (uint4*)(xg + (size_t)slot * DIM);
    d[threadIdx.x] = s[threadIdx.x];
}

// ---------------- bf16 MFMA GEMM: C[M][N] = A[M][K] * Bt[N][K]^T (+bias, opt GELU) ----------------
// m97 structure: 128x128 tile, BK=32, 4 waves of 4x4 16x16x32 MFMA, global_load_lds width 16.
__launch_bounds__(256)
__global__ void gemm_bt(const unsigned short* __restrict__ A, const unsigned short* __restrict__ Bt,
                        const float* __restrict__ bias, void* __restrict__ Cout,
                        int M, int N, int K, int gelu_bf16_out) {
    __shared__ unsigned short As[128 * 32];
    __shared__ unsigned short Bs[128 * 32];
    const int t = threadIdx.x;
    const int row_a0 = blockIdx.x * 128;
    const int row_b0 = blockIdx.y * 128;

    const int wave = t >> 6, lane = t & 63;
    const int wm = (wave & 1) * 64, wn = (wave >> 1) * 64;
    const int quad = lane >> 4, l16 = lane & 15;

    // staging: idx = r*256 + t; row = idx>>2, kcol = (idx&3)*8, lds elem off = idx*8
    const int sr = t >> 2;
    const int sc = (t & 3) * 8;
    const unsigned short* Aptr = A + (size_t)(row_a0 + sr) * K + sc;
    const unsigned short* Bptr = Bt + (size_t)(row_b0 + sr) * K + sc;
    unsigned short* AsP = As + t * 8;
    unsigned short* BsP = Bs + t * 8;
    const size_t stride64 = (size_t)64 * K;

    floatx4 acc[4][4] = {};

    for (int k0 = 0; k0 < K; k0 += 32) {
        __syncthreads();                       // previous compute done before overwrite
        load16_lds(Aptr,            AsP);
        load16_lds(Aptr + stride64, AsP + 2048);
        load16_lds(Bptr,            BsP);
        load16_lds(Bptr + stride64, BsP + 2048);
        Aptr += 32; Bptr += 32;
        __builtin_amdgcn_s_waitcnt(0);         // drain vmcnt/lgkm before barrier
        __syncthreads();

        short8 af[4], bfv[4];
        #pragma unroll
        for (int i = 0; i < 4; i++)
            af[i] = *(const short8*)(As + (wm + i * 16 + l16) * 32 + quad * 8);
        #pragma unroll
        for (int j = 0; j < 4; j++)
            bfv[j] = *(const short8*)(Bs + (wn + j * 16 + l16) * 32 + quad * 8);
        #pragma unroll
        for (int i = 0; i < 4; i++)
            #pragma unroll
            for (int j = 0; j < 4; j++)
                acc[i][j] = __builtin_amdgcn_mfma_f32_16x16x32_bf16(af[i], bfv[j], acc[i][j], 0, 0, 0);
    }

    // epilogue: C/D layout col = lane&15, row = quad*4 + r
    if (gelu_bf16_out) {
        unsigned short* C = (unsigned short*)Cout;
        #pragma unroll
        for (int i = 0; i < 4; i++) {
            #pragma unroll
            for (int j = 0; j < 4; j++) {
                int cc = row_b0 + wn + j * 16 + l16;
                float bv = bias[cc];
                #pragma unroll
                for (int r = 0; r < 4; r++) {
                    int rr = row_a0 + wm + i * 16 + quad * 4 + r;
                    float v = acc[i][j][r] + bv;
                    v = 0.5f * v * (1.0f + erff(v * 0.70710678118654752f));
                    C[(size_t)rr * N + cc] = bf16b(v);
                }
            }
        }
    } else {
        float* C = (float*)Cout;
        #pragma unroll
        for (int i = 0; i < 4; i++) {
            #pragma unroll
            for (int j = 0; j < 4; j++) {
                int cc = row_b0 + wn + j * 16 + l16;
                float bv = bias[cc];
                #pragma unroll
                for (int r = 0; r < 4; r++) {
                    int rr = row_a0 + wm + i * 16 + quad * 4 + r;
                    C[(size_t)rr * N + cc] = acc[i][j][r] + bv;
                }
            }
        }
    }
}

// ---------------- final: out = x + scatter(ffn)*gamma ----------------
__launch_bounds__(256)
__global__ void combine(const float* __restrict__ x, const float* __restrict__ ffn,
                        const int* __restrict__ slot_map, const float* __restrict__ gamma,
                        float* __restrict__ out) {
    const int row = blockIdx.x;
    const int s = slot_map[row];
    const int t = threadIdx.x;
    const float4* x4 = (const float4*)(x + (size_t)row * DIM);
    const float4* g4 = (const float4*)gamma;
    float4* o4 = (float4*)(out + (size_t)row * DIM);
    if (s >= 0) {
        const float4* f4 = (const float4*)(ffn + (size_t)s * DIM);
        #pragma unroll
        for (int i = 0; i < 2; i++) {
            int idx = t + i * 256;
            float4 xv = x4[idx], fv = f4[idx], gv = g4[idx];
            float4 ov;
            ov.x = xv.x + fv.x * gv.x;
            ov.y = xv.y + fv.y * gv.y;
            ov.z = xv.z + fv.z * gv.z;
            ov.w = xv.w + fv.w * gv.w;
            o4[idx] = ov;
        }
    } else {
        #pragma unroll
        for (int i = 0; i < 2; i++) {
            int idx = t + i * 256;
            o4[idx] = x4[idx];
        }
    }
}

extern "C" void kernel_launch(void* const* d_in, const int* in_sizes, int n_in,
                              void* d_out, int out_size, void* d_ws, size_t ws_size,
                              hipStream_t stream) {
    const float* x     = (const float*)d_in[0];
    const float* nw    = (const float*)d_in[1];
    const float* rw    = (const float*)d_in[2];
    const float* rb    = (const float*)d_in[3];
    const float* w1    = (const float*)d_in[4];
    const float* b1    = (const float*)d_in[5];
    const float* w2    = (const float*)d_in[6];
    const float* b2    = (const float*)d_in[7];
    const float* gamma = (const float*)d_in[8];
    float* out = (float*)d_out;

    char* ws = (char*)d_ws;
    size_t off = 0;
    auto alloc = [&](size_t bytes) -> void* {
        void* p = ws + off;
        off = (off + bytes + 255) & ~(size_t)255;
        return p;
    };
    unsigned short* xn  = (unsigned short*)alloc((size_t)NTOK * DIM * 2);   // 32 MB (reused as ffn)
    unsigned short* w1t = (unsigned short*)alloc((size_t)HID * DIM * 2);    // 32 MB
    unsigned short* w2t = (unsigned short*)alloc((size_t)DIM * HID * 2);    // 32 MB
    unsigned short* xg  = (unsigned short*)alloc((size_t)KCAP * DIM * 2);   // 16 MB
    unsigned short* h   = (unsigned short*)alloc((size_t)KCAP * HID * 2);   // 64 MB
    float* logits       = (float*)alloc((size_t)NTOK * 4);
    int* cnt            = (int*)alloc((size_t)NTOK * 4);
    int* counter        = (int*)alloc(256);
    int* sel_idx        = (int*)alloc((size_t)KCAP * 4);
    int* slot_map       = (int*)alloc((size_t)NTOK * 4);
    float* ffn          = (float*)xn;  // alias: xn dead after gather_rows, same 32 MB

    hipMemsetAsync(cnt, 0, (size_t)NTOK * 4, stream);
    hipMemsetAsync(counter, 0, 4, stream);
    hipMemsetAsync(slot_map, 0xFF, (size_t)NTOK * 4, stream);

    rmsnorm_router<<<NTOK, 256, 0, stream>>>(x, nw, rw, rb, xn, logits);
    transpose_bf16<<<dim3(HID / 32, DIM / 32), dim3(32, 8), 0, stream>>>(w1, w1t, DIM, HID);
    transpose_bf16<<<dim3(DIM / 32, HID / 32), dim3(32, 8), 0, stream>>>(w2, w2t, HID, DIM);
    rank_partial<<<dim3(NTOK / 256, NTOK / JCHUNK), 256, 0, stream>>>(logits, cnt);
    select_compact<<<NTOK / 256, 256, 0, stream>>>(cnt, counter, sel_idx, slot_map);
    gather_rows<<<KCAP, 256, 0, stream>>>(xn, sel_idx, xg);
    gemm_bt<<<dim3(KCAP / 128, HID / 128), 256, 0, stream>>>(xg, w1t, b1, (void*)h,
                                                             KCAP, HID, DIM, 1);
    gemm_bt<<<dim3(KCAP / 128, DIM / 128), 256, 0, stream>>>(h, w2t, b2, (void*)ffn,
                                                             KCAP, DIM, HID, 0);
    combine<<<NTOK, 256, 0, stream>>>(x, ffn, slot_map, gamma, out);
}

// Round 2
// 644.298 us; speedup vs baseline: 1.0550x; 1.0550x over previous
//
#include <hip/hip_runtime.h>
#include <hip/hip_bf16.h>
#include <math.h>
#include <stdint.h>

#define DIM 2048
#define HID 8192
#define NTOK 8192
#define KCAP 4096

// per-tensor fp8 scales (undone in epilogues)
#define S_W1 64.0f
#define S_H  16.0f
#define S_W2 32.0f

typedef __attribute__((ext_vector_type(4))) float floatx4;

__device__ __forceinline__ unsigned int pk4_fp8(float a, float b, float c, float d) {
    int v = __builtin_amdgcn_cvt_pk_fp8_f32(a, b, 0, false);
    v = __builtin_amdgcn_cvt_pk_fp8_f32(c, d, v, true);
    return (unsigned int)v;
}
__device__ __forceinline__ unsigned char fp8b(float a) {
    return (unsigned char)(__builtin_amdgcn_cvt_pk_fp8_f32(a, 0.0f, 0, false) & 0xff);
}

typedef const __attribute__((address_space(1))) unsigned int* gu32p;
typedef __attribute__((address_space(3))) unsigned int* lu32p;
__device__ __forceinline__ void load16_lds(const void* g, void* l) {
    __builtin_amdgcn_global_load_lds((gu32p)g, (lu32p)l, 16, 0, 0);
}

// ---------------- RMSNorm + router logit + out=x passthrough + fp8 x_norm ----------------
__launch_bounds__(256)
__global__ void rmsnorm_router(const float* __restrict__ x,
                               const float* __restrict__ nw,
                               const float* __restrict__ rw,
                               const float* __restrict__ rb,
                               unsigned char* __restrict__ xq,
                               float* __restrict__ logits,
                               float* __restrict__ out) {
    const int row = blockIdx.x;
    const int t = threadIdx.x;
    const float4* x4 = (const float4*)(x + (size_t)row * DIM);
    float4 a = x4[t];
    float4 b = x4[t + 256];
    float ss = a.x*a.x + a.y*a.y + a.z*a.z + a.w*a.w
             + b.x*b.x + b.y*b.y + b.z*b.z + b.w*b.w;
    for (int off = 32; off > 0; off >>= 1) ss += __shfl_down(ss, off, 64);
    __shared__ float red[4];
    int wave = t >> 6, lane = t & 63;
    if (lane == 0) red[wave] = ss;
    __syncthreads();
    float tot = red[0] + red[1] + red[2] + red[3];
    float rs = rsqrtf(tot / (float)DIM + 1e-6f);

    // out = x passthrough (selected rows get overwritten by GEMM2 epilogue)
    float4* o4 = (float4*)(out + (size_t)row * DIM);
    o4[t] = a;
    o4[t + 256] = b;

    const float4* nw4 = (const float4*)nw;
    const float4* rw4 = (const float4*)rw;
    float4 w0 = nw4[t], w1 = nw4[t + 256];
    float4 r0 = rw4[t], r1 = rw4[t + 256];
    float4 n0, n1;
    n0.x = a.x*rs*w0.x; n0.y = a.y*rs*w0.y; n0.z = a.z*rs*w0.z; n0.w = a.w*rs*w0.w;
    n1.x = b.x*rs*w1.x; n1.y = b.y*rs*w1.y; n1.z = b.z*rs*w1.z; n1.w = b.w*rs*w1.w;
    float dot = n0.x*r0.x + n0.y*r0.y + n0.z*r0.z + n0.w*r0.w
              + n1.x*r1.x + n1.y*r1.y + n1.z*r1.z + n1.w*r1.w;

    unsigned char* xr = xq + (size_t)row * DIM;
    *(unsigned int*)(xr + 4*t)        = pk4_fp8(n0.x, n0.y, n0.z, n0.w);
    *(unsigned int*)(xr + 4*t + 1024) = pk4_fp8(n1.x, n1.y, n1.z, n1.w);

    for (int off = 32; off > 0; off >>= 1) dot += __shfl_down(dot, off, 64);
    __syncthreads();                 // protect red reuse
    if (lane == 0) red[wave] = dot;
    __syncthreads();
    if (t == 0) logits[row] = red[0] + red[1] + red[2] + red[3] + rb[0];
}

// ---------------- fp32 -> fp8 transpose with scale (dst[c][r] = src[r][c]*scale) ----------------
__launch_bounds__(256)
__global__ void transpose_fp8(const float* __restrict__ src, unsigned char* __restrict__ dst,
                              int R, int C, float scale) {
    __shared__ float tile[32][33];
    int c0 = blockIdx.x * 32, r0 = blockIdx.y * 32;
    int tx = threadIdx.x, ty = threadIdx.y;
    #pragma unroll
    for (int i = 0; i < 32; i += 8)
        tile[ty + i][tx] = src[(size_t)(r0 + ty + i) * C + c0 + tx];
    __syncthreads();
    #pragma unroll
    for (int i = 0; i < 32; i += 8)
        dst[(size_t)(c0 + ty + i) * R + r0 + tx] = fp8b(tile[tx][ty + i] * scale);
}

// ---------------- exact rank counting (jax top_k tie-break: lower index wins) ----------------
#define JCHUNK 1024
__launch_bounds__(256)
__global__ void rank_partial(const float* __restrict__ logits, int* __restrict__ cnt) {
    __shared__ float ls[JCHUNK];
    const int j0 = blockIdx.y * JCHUNK;
    for (int j = threadIdx.x; j < JCHUNK; j += 256) ls[j] = logits[j0 + j];
    __syncthreads();
    const int i = blockIdx.x * 256 + threadIdx.x;
    const float my = logits[i];
    int c = 0;
    #pragma unroll 8
    for (int j = 0; j < JCHUNK; j++) {
        float v = ls[j];
        c += (v > my) || (v == my && (j0 + j) < i);
    }
    atomicAdd(&cnt[i], c);
}

__launch_bounds__(256)
__global__ void select_compact(const int* __restrict__ cnt, int* __restrict__ counter,
                               int* __restrict__ sel_idx) {
    const int i = blockIdx.x * 256 + threadIdx.x;
    const bool sel = cnt[i] < KCAP;
    unsigned long long m = __ballot(sel);
    int lane = threadIdx.x & 63;
    int base = 0;
    if (lane == 0) base = atomicAdd(counter, (int)__popcll(m));
    base = __shfl(base, 0, 64);
    if (sel) {
        int pos = base + (int)__popcll(m & ((1ull << lane) - 1ull));
        sel_idx[pos] = i;
    }
}

// ---------------- fp8 MFMA GEMM: C[M][N] = A[M][K] * Bt[N][K]^T ----------------
// 128x128 tile, BK=32 (bytes), 4 waves x (4x4) 16x16x32 fp8 MFMA, global_load_lds width 16.
// MODE 1: A rows gathered via sel_idx; epilogue acc/S + b1 -> gelu -> fp8*S_H into h.
// MODE 2: A = h (slot-major); epilogue out[token] = x[token] + (acc/S + b2)*gamma.
template<int MODE>
__launch_bounds__(256)
__global__ void gemm_fp8(const unsigned char* __restrict__ A,
                         const unsigned char* __restrict__ Bt,
                         const float* __restrict__ bias,
                         const int* __restrict__ sel_idx,
                         const float* __restrict__ x,
                         const float* __restrict__ gamma,
                         void* __restrict__ Cout,
                         int N, int K, float inv_scale) {
    __shared__ __align__(16) unsigned char As[128 * 32];
    __shared__ __align__(16) unsigned char Bs[128 * 32];
    const int t = threadIdx.x;
    const int row_a0 = blockIdx.x * 128;
    const int row_b0 = blockIdx.y * 128;

    const int wave = t >> 6, lane = t & 63;
    const int wm = (wave & 1) * 64, wn = (wave >> 1) * 64;
    const int quad = lane >> 4, l16 = lane & 15;

    // staging: lane t covers row sr = t>>1, byte col sc = (t&1)*16; LDS offset t*16
    const int sr = t >> 1;
    const int sc = (t & 1) * 16;
    long arow;
    if (MODE == 1) arow = sel_idx[row_a0 + sr];
    else           arow = row_a0 + sr;
    const unsigned char* Aptr = A + arow * (long)K + sc;
    const unsigned char* Bptr = Bt + (size_t)(row_b0 + sr) * K + sc;
    unsigned char* AsP = As + t * 16;
    unsigned char* BsP = Bs + t * 16;

    floatx4 acc[4][4] = {};

    for (int k0 = 0; k0 < K; k0 += 32) {
        __syncthreads();                       // previous compute done before overwrite
        load16_lds(Aptr, AsP);
        load16_lds(Bptr, BsP);
        Aptr += 32; Bptr += 32;
        __builtin_amdgcn_s_waitcnt(0);         // drain vmcnt before barrier
        __syncthreads();

        long af[4], bfv[4];
        #pragma unroll
        for (int i = 0; i < 4; i++)
            af[i] = *(const long*)(As + (wm + i * 16 + l16) * 32 + quad * 8);
        #pragma unroll
        for (int j = 0; j < 4; j++)
            bfv[j] = *(const long*)(Bs + (wn + j * 16 + l16) * 32 + quad * 8);
        #pragma unroll
        for (int i = 0; i < 4; i++)
            #pragma unroll
            for (int j = 0; j < 4; j++)
                acc[i][j] = __builtin_amdgcn_mfma_f32_16x16x32_fp8_fp8(af[i], bfv[j], acc[i][j], 0, 0, 0);
    }

    // C/D layout: col = lane&15 (within 16-tile), row = quad*4 + r
    if (MODE == 1) {
        unsigned char* C = (unsigned char*)Cout;
        #pragma unroll
        for (int i = 0; i < 4; i++) {
            #pragma unroll
            for (int j = 0; j < 4; j++) {
                int cc = row_b0 + wn + j * 16 + l16;
                float bv = bias[cc];
                #pragma unroll
                for (int r = 0; r < 4; r++) {
                    int rr = row_a0 + wm + i * 16 + quad * 4 + r;
                    float v = acc[i][j][r] * inv_scale + bv;
                    v = 0.5f * v * (1.0f + erff(v * 0.70710678118654752f));
                    C[(size_t)rr * N + cc] = fp8b(v * S_H);
                }
            }
        }
    } else {
        float* O = (float*)Cout;
        #pragma unroll
        for (int i = 0; i < 4; i++) {
            #pragma unroll
            for (int r = 0; r < 4; r++) {
                int slot = row_a0 + wm + i * 16 + quad * 4 + r;
                long token = sel_idx[slot];
                const float* xrow = x + token * (long)DIM;
                float* orow = O + token * (long)DIM;
                #pragma unroll
                for (int j = 0; j < 4; j++) {
                    int cc = row_b0 + wn + j * 16 + l16;
                    float v = acc[i][j][r] * inv_scale + bias[cc];
                    orow[cc] = xrow[cc] + v * gamma[cc];
                }
            }
        }
    }
}

extern "C" void kernel_launch(void* const* d_in, const int* in_sizes, int n_in,
                              void* d_out, int out_size, void* d_ws, size_t ws_size,
                              hipStream_t stream) {
    const float* x     = (const float*)d_in[0];
    const float* nw    = (const float*)d_in[1];
    const float* rw    = (const float*)d_in[2];
    const float* rb    = (const float*)d_in[3];
    const float* w1    = (const float*)d_in[4];
    const float* b1    = (const float*)d_in[5];
    const float* w2    = (const float*)d_in[6];
    const float* b2    = (const float*)d_in[7];
    const float* gamma = (const float*)d_in[8];
    float* out = (float*)d_out;

    char* ws = (char*)d_ws;
    size_t off = 0;
    auto alloc = [&](size_t bytes) -> void* {
        void* p = ws + off;
        off = (off + bytes + 255) & ~(size_t)255;
        return p;
    };
    unsigned char* xq  = (unsigned char*)alloc((size_t)NTOK * DIM);   // 16 MB fp8 x_norm
    unsigned char* w1q = (unsigned char*)alloc((size_t)HID * DIM);    // 16 MB fp8 w1^T [HID][DIM]
    unsigned char* w2q = (unsigned char*)alloc((size_t)DIM * HID);    // 16 MB fp8 w2^T [DIM][HID]
    unsigned char* h   = (unsigned char*)alloc((size_t)KCAP * HID);   // 32 MB fp8 hidden
    float* logits      = (float*)alloc((size_t)NTOK * 4);
    int* cnt           = (int*)alloc((size_t)NTOK * 4);
    int* counter       = (int*)alloc(256);
    int* sel_idx       = (int*)alloc((size_t)KCAP * 4);

    hipMemsetAsync(cnt, 0, (size_t)NTOK * 4, stream);
    hipMemsetAsync(counter, 0, 4, stream);

    rmsnorm_router<<<NTOK, 256, 0, stream>>>(x, nw, rw, rb, xq, logits, out);
    transpose_fp8<<<dim3(HID / 32, DIM / 32), dim3(32, 8), 0, stream>>>(w1, w1q, DIM, HID, S_W1);
    transpose_fp8<<<dim3(DIM / 32, HID / 32), dim3(32, 8), 0, stream>>>(w2, w2q, HID, DIM, S_W2);
    rank_partial<<<dim3(NTOK / 256, NTOK / JCHUNK), 256, 0, stream>>>(logits, cnt);
    select_compact<<<NTOK / 256, 256, 0, stream>>>(cnt, counter, sel_idx);
    gemm_fp8<1><<<dim3(KCAP / 128, HID / 128), 256, 0, stream>>>(
        xq, w1q, b1, sel_idx, nullptr, nullptr, (void*)h, HID, DIM, 1.0f / S_W1);
    gemm_fp8<2><<<dim3(KCAP / 128, DIM / 128), 256, 0, stream>>>(
        h, w2q, b2, sel_idx, x, gamma, (void*)out, DIM, HID, 1.0f / (S_H * S_W2));
}

// Round 3
// 452.453 us; speedup vs baseline: 1.5023x; 1.4240x over previous
//
#include <hip/hip_runtime.h>
#include <hip/hip_bf16.h>
#include <math.h>
#include <stdint.h>

#define DIM 2048
#define HID 8192
#define NTOK 8192
#define KCAP 4096

// per-tensor fp8 scales (undone in epilogues)
#define S_W1 64.0f
#define S_H  16.0f
#define S_W2 32.0f

typedef __attribute__((ext_vector_type(4))) float floatx4;
typedef __attribute__((ext_vector_type(4))) int   intx4;
typedef __attribute__((ext_vector_type(8))) int   intx8;

__device__ __forceinline__ unsigned int pk4_fp8(float a, float b, float c, float d) {
    int v = __builtin_amdgcn_cvt_pk_fp8_f32(a, b, 0, false);
    v = __builtin_amdgcn_cvt_pk_fp8_f32(c, d, v, true);
    return (unsigned int)v;
}
__device__ __forceinline__ unsigned char fp8b(float a) {
    return (unsigned char)(__builtin_amdgcn_cvt_pk_fp8_f32(a, 0.0f, 0, false) & 0xff);
}

typedef const __attribute__((address_space(1))) unsigned int* gu32p;
typedef __attribute__((address_space(3))) unsigned int* lu32p;
__device__ __forceinline__ void load16_lds(const void* g, void* l) {
    __builtin_amdgcn_global_load_lds((gu32p)g, (lu32p)l, 16, 0, 0);
}

// ---------------- RMSNorm + router logit + out=x passthrough + fp8 x_norm ----------------
__launch_bounds__(256)
__global__ void rmsnorm_router(const float* __restrict__ x,
                               const float* __restrict__ nw,
                               const float* __restrict__ rw,
                               const float* __restrict__ rb,
                               unsigned char* __restrict__ xq,
                               float* __restrict__ logits,
                               float* __restrict__ out) {
    const int row = blockIdx.x;
    const int t = threadIdx.x;
    const float4* x4 = (const float4*)(x + (size_t)row * DIM);
    float4 a = x4[t];
    float4 b = x4[t + 256];
    float ss = a.x*a.x + a.y*a.y + a.z*a.z + a.w*a.w
             + b.x*b.x + b.y*b.y + b.z*b.z + b.w*b.w;
    for (int off = 32; off > 0; off >>= 1) ss += __shfl_down(ss, off, 64);
    __shared__ float red[4];
    int wave = t >> 6, lane = t & 63;
    if (lane == 0) red[wave] = ss;
    __syncthreads();
    float tot = red[0] + red[1] + red[2] + red[3];
    float rs = rsqrtf(tot / (float)DIM + 1e-6f);

    // out = x passthrough (selected rows get overwritten by GEMM2 epilogue)
    float4* o4 = (float4*)(out + (size_t)row * DIM);
    o4[t] = a;
    o4[t + 256] = b;

    const float4* nw4 = (const float4*)nw;
    const float4* rw4 = (const float4*)rw;
    float4 w0 = nw4[t], w1 = nw4[t + 256];
    float4 r0 = rw4[t], r1 = rw4[t + 256];
    float4 n0, n1;
    n0.x = a.x*rs*w0.x; n0.y = a.y*rs*w0.y; n0.z = a.z*rs*w0.z; n0.w = a.w*rs*w0.w;
    n1.x = b.x*rs*w1.x; n1.y = b.y*rs*w1.y; n1.z = b.z*rs*w1.z; n1.w = b.w*rs*w1.w;
    float dot = n0.x*r0.x + n0.y*r0.y + n0.z*r0.z + n0.w*r0.w
              + n1.x*r1.x + n1.y*r1.y + n1.z*r1.z + n1.w*r1.w;

    unsigned char* xr = xq + (size_t)row * DIM;
    *(unsigned int*)(xr + 4*t)        = pk4_fp8(n0.x, n0.y, n0.z, n0.w);
    *(unsigned int*)(xr + 4*t + 1024) = pk4_fp8(n1.x, n1.y, n1.z, n1.w);

    for (int off = 32; off > 0; off >>= 1) dot += __shfl_down(dot, off, 64);
    __syncthreads();                 // protect red reuse
    if (lane == 0) red[wave] = dot;
    __syncthreads();
    if (t == 0) logits[row] = red[0] + red[1] + red[2] + red[3] + rb[0];
}

// ---------------- fp32 -> fp8 transpose with scale (dst[c][r] = src[r][c]*scale) ----------------
__launch_bounds__(256)
__global__ void transpose_fp8(const float* __restrict__ src, unsigned char* __restrict__ dst,
                              int R, int C, float scale) {
    __shared__ float tile[32][33];
    int c0 = blockIdx.x * 32, r0 = blockIdx.y * 32;
    int tx = threadIdx.x, ty = threadIdx.y;
    #pragma unroll
    for (int i = 0; i < 32; i += 8)
        tile[ty + i][tx] = src[(size_t)(r0 + ty + i) * C + c0 + tx];
    __syncthreads();
    #pragma unroll
    for (int i = 0; i < 32; i += 8)
        dst[(size_t)(c0 + ty + i) * R + r0 + tx] = fp8b(tile[tx][ty + i] * scale);
}

// ---------------- exact rank counting (jax top_k tie-break: lower index wins) ----------------
#define JCHUNK 1024
__launch_bounds__(256)
__global__ void rank_partial(const float* __restrict__ logits, int* __restrict__ cnt) {
    __shared__ float ls[JCHUNK];
    const int j0 = blockIdx.y * JCHUNK;
    for (int j = threadIdx.x; j < JCHUNK; j += 256) ls[j] = logits[j0 + j];
    __syncthreads();
    const int i = blockIdx.x * 256 + threadIdx.x;
    const float my = logits[i];
    int c = 0;
    #pragma unroll 8
    for (int j = 0; j < JCHUNK; j++) {
        float v = ls[j];
        c += (v > my) || (v == my && (j0 + j) < i);
    }
    atomicAdd(&cnt[i], c);
}

__launch_bounds__(256)
__global__ void select_compact(const int* __restrict__ cnt, int* __restrict__ counter,
                               int* __restrict__ sel_idx) {
    const int i = blockIdx.x * 256 + threadIdx.x;
    const bool sel = cnt[i] < KCAP;
    unsigned long long m = __ballot(sel);
    int lane = threadIdx.x & 63;
    int base = 0;
    if (lane == 0) base = atomicAdd(counter, (int)__popcll(m));
    base = __shfl(base, 0, 64);
    if (sel) {
        int pos = base + (int)__popcll(m & ((1ull << lane) - 1ull));
        sel_idx[pos] = i;
    }
}

// ---------------- MX-fp8 MFMA GEMM: C[M][N] = A[M][K] * Bt[N][K]^T ----------------
// 128x128 tile, BK=128 bytes, 4 waves x (4x4) 16x16x128 f8f6f4 MFMA (scale=1.0),
// global_load_lds width 16, 16B-chunk XOR swizzle (chunk ^= row&7) for conflict-free ds_read.
// MODE 1: A rows gathered via sel_idx; epilogue acc/S + b1 -> gelu -> fp8*S_H into h.
// MODE 2: A = h (slot-major); epilogue out[token] = x[token] + (acc/S + b2)*gamma.
template<int MODE>
__launch_bounds__(256)
__global__ void gemm_mx(const unsigned char* __restrict__ A,
                        const unsigned char* __restrict__ Bt,
                        const float* __restrict__ bias,
                        const int* __restrict__ sel_idx,
                        const float* __restrict__ x,
                        const float* __restrict__ gamma,
                        void* __restrict__ Cout,
                        int N, int K, float inv_scale) {
    __shared__ __align__(16) unsigned char As[128 * 128];
    __shared__ __align__(16) unsigned char Bs[128 * 128];
    const int t = threadIdx.x;
    const int row_a0 = blockIdx.x * 128;
    const int row_b0 = blockIdx.y * 128;

    const int wave = t >> 6, lane = t & 63;
    const int wm = (wave & 1) * 64, wn = (wave >> 1) * 64;
    const int quad = lane >> 4, l16 = lane & 15;

    // staging: thread t fills LDS offset (cc*4096 + t*16) = row (cc*32 + t>>3), chunk t&7.
    // swizzled: LDS chunk c holds global chunk c ^ (row&7).
    const int srow = t >> 3;                        // 0..31
    const int schunk = (t & 7) ^ (srow & 7);        // global 16B-chunk to fetch
    const unsigned char* ap[4];
    const unsigned char* bp[4];
    unsigned char* al[4];
    unsigned char* bl[4];
    #pragma unroll
    for (int cc = 0; cc < 4; cc++) {
        int row = cc * 32 + srow;
        long arow;
        if (MODE == 1) arow = sel_idx[row_a0 + row];
        else           arow = row_a0 + row;
        ap[cc] = A + arow * (long)K + schunk * 16;
        bp[cc] = Bt + (size_t)(row_b0 + row) * K + schunk * 16;
        al[cc] = As + cc * 4096 + t * 16;
        bl[cc] = Bs + cc * 4096 + t * 16;
    }

    floatx4 acc[4][4] = {};
    const int sw = l16 & 7;                          // read-side swizzle key (row&7)
    const int c0 = (2 * quad) ^ sw;                  // 16B chunk of this lane's k-block lo half
    const int c1 = c0 ^ 1;                           // hi half

    for (int k0 = 0; k0 < K; k0 += 128) {
        __syncthreads();                             // previous compute done before overwrite
        #pragma unroll
        for (int cc = 0; cc < 4; cc++) { load16_lds(ap[cc], al[cc]); ap[cc] += 128; }
        #pragma unroll
        for (int cc = 0; cc < 4; cc++) { load16_lds(bp[cc], bl[cc]); bp[cc] += 128; }
        __builtin_amdgcn_s_waitcnt(0);               // drain vmcnt before barrier
        __syncthreads();

        intx8 af[4];
        #pragma unroll
        for (int i = 0; i < 4; i++) {
            const unsigned char* base = As + (wm + i * 16 + l16) * 128;
            intx4 lo = *(const intx4*)(base + c0 * 16);
            intx4 hi = *(const intx4*)(base + c1 * 16);
            af[i] = intx8{lo.x, lo.y, lo.z, lo.w, hi.x, hi.y, hi.z, hi.w};
        }
        #pragma unroll
        for (int j = 0; j < 4; j++) {
            const unsigned char* base = Bs + (wn + j * 16 + l16) * 128;
            intx4 lo = *(const intx4*)(base + c0 * 16);
            intx4 hi = *(const intx4*)(base + c1 * 16);
            intx8 bfv = intx8{lo.x, lo.y, lo.z, lo.w, hi.x, hi.y, hi.z, hi.w};
            #pragma unroll
            for (int i = 0; i < 4; i++)
                acc[i][j] = __builtin_amdgcn_mfma_scale_f32_16x16x128_f8f6f4(
                    af[i], bfv, acc[i][j], 0, 0,      // cbsz=fp8, blgp=fp8
                    0, 0x7F7F7F7F,                    // opsel_a, scale_a = 1.0
                    0, 0x7F7F7F7F);                   // opsel_b, scale_b = 1.0
        }
    }

    // C/D layout: col = lane&15 (within 16-tile), row = quad*4 + r
    if (MODE == 1) {
        unsigned char* C = (unsigned char*)Cout;
        #pragma unroll
        for (int i = 0; i < 4; i++) {
            #pragma unroll
            for (int j = 0; j < 4; j++) {
                int cc = row_b0 + wn + j * 16 + l16;
                float bv = bias[cc];
                #pragma unroll
                for (int r = 0; r < 4; r++) {
                    int rr = row_a0 + wm + i * 16 + quad * 4 + r;
                    float v = acc[i][j][r] * inv_scale + bv;
                    v = 0.5f * v * (1.0f + erff(v * 0.70710678118654752f));
                    C[(size_t)rr * N + cc] = fp8b(v * S_H);
                }
            }
        }
    } else {
        float* O = (float*)Cout;
        #pragma unroll
        for (int i = 0; i < 4; i++) {
            #pragma unroll
            for (int r = 0; r < 4; r++) {
                int slot = row_a0 + wm + i * 16 + quad * 4 + r;
                long token = sel_idx[slot];
                const float* xrow = x + token * (long)DIM;
                float* orow = O + token * (long)DIM;
                #pragma unroll
                for (int j = 0; j < 4; j++) {
                    int cc = row_b0 + wn + j * 16 + l16;
                    float v = acc[i][j][r] * inv_scale + bias[cc];
                    orow[cc] = xrow[cc] + v * gamma[cc];
                }
            }
        }
    }
}

extern "C" void kernel_launch(void* const* d_in, const int* in_sizes, int n_in,
                              void* d_out, int out_size, void* d_ws, size_t ws_size,
                              hipStream_t stream) {
    const float* x     = (const float*)d_in[0];
    const float* nw    = (const float*)d_in[1];
    const float* rw    = (const float*)d_in[2];
    const float* rb    = (const float*)d_in[3];
    const float* w1    = (const float*)d_in[4];
    const float* b1    = (const float*)d_in[5];
    const float* w2    = (const float*)d_in[6];
    const float* b2    = (const float*)d_in[7];
    const float* gamma = (const float*)d_in[8];
    float* out = (float*)d_out;

    char* ws = (char*)d_ws;
    size_t off = 0;
    auto alloc = [&](size_t bytes) -> void* {
        void* p = ws + off;
        off = (off + bytes + 255) & ~(size_t)255;
        return p;
    };
    unsigned char* xq  = (unsigned char*)alloc((size_t)NTOK * DIM);   // 16 MB fp8 x_norm
    unsigned char* w1q = (unsigned char*)alloc((size_t)HID * DIM);    // 16 MB fp8 w1^T [HID][DIM]
    unsigned char* w2q = (unsigned char*)alloc((size_t)DIM * HID);    // 16 MB fp8 w2^T [DIM][HID]
    unsigned char* h   = (unsigned char*)alloc((size_t)KCAP * HID);   // 32 MB fp8 hidden
    float* logits      = (float*)alloc((size_t)NTOK * 4);
    int* cnt           = (int*)alloc((size_t)NTOK * 4);
    int* counter       = (int*)alloc(256);
    int* sel_idx       = (int*)alloc((size_t)KCAP * 4);

    hipMemsetAsync(cnt, 0, (size_t)NTOK * 4, stream);
    hipMemsetAsync(counter, 0, 4, stream);

    rmsnorm_router<<<NTOK, 256, 0, stream>>>(x, nw, rw, rb, xq, logits, out);
    transpose_fp8<<<dim3(HID / 32, DIM / 32), dim3(32, 8), 0, stream>>>(w1, w1q, DIM, HID, S_W1);
    transpose_fp8<<<dim3(DIM / 32, HID / 32), dim3(32, 8), 0, stream>>>(w2, w2q, HID, DIM, S_W2);
    rank_partial<<<dim3(NTOK / 256, NTOK / JCHUNK), 256, 0, stream>>>(logits, cnt);
    select_compact<<<NTOK / 256, 256, 0, stream>>>(cnt, counter, sel_idx);
    gemm_mx<1><<<dim3(KCAP / 128, HID / 128), 256, 0, stream>>>(
        xq, w1q, b1, sel_idx, nullptr, nullptr, (void*)h, HID, DIM, 1.0f / S_W1);
    gemm_mx<2><<<dim3(KCAP / 128, DIM / 128), 256, 0, stream>>>(
        h, w2q, b2, sel_idx, x, gamma, (void*)out, DIM, HID, 1.0f / (S_H * S_W2));
}